// Round 7
// baseline (1891.868 us; speedup 1.0000x reference)
//
#include <hip/hip_runtime.h>
#include <hip/hip_bf16.h>

#define BS_   2048
#define HID_  512
#define PH_   32

typedef _Float16 half8 __attribute__((ext_vector_type(8)));
typedef float floatx4 __attribute__((ext_vector_type(4)));

__device__ __forceinline__ float sigf(float x) { return 1.f / (1.f + __expf(-x)); }
__device__ __forceinline__ float tanhfast(float x) {
    float e = __expf(2.f * x);          // e=inf -> 1, e->0 -> -1 : safe at extremes
    return 1.f - 2.f / (e + 1.f);
}

// ---------------------------------------------------------------------------
// Prep: fp16 weights (W_ih and W_ih+W_hh), combined bias, z16, zero the
// per-(t, ib, wv) wave counters (2048 ints).
// ---------------------------------------------------------------------------
__global__ __launch_bounds__(256) void prep_kernel(
    const float* __restrict__ Wih, const float* __restrict__ Whh,
    const float* __restrict__ bih, const float* __restrict__ bhh,
    const float* __restrict__ z,
    _Float16* __restrict__ wih16, _Float16* __restrict__ wsum16,
    _Float16* __restrict__ z16, float* __restrict__ bsum,
    int* __restrict__ cnt)
{
    int i = blockIdx.x * 256 + threadIdx.x;          // [0, 1048576)
    if (i < BS_ * HID_) z16[i] = (_Float16)z[i];
    if (i < 4 * HID_ * HID_) {
        float a = Wih[i];
        wih16[i]  = (_Float16)a;
        wsum16[i] = (_Float16)(a + Whh[i]);
    }
    if (i < 4 * HID_) bsum[i] = bih[i] + bhh[i];
    if (i < 2048) cnt[i] = 0;
}

// ---------------------------------------------------------------------------
__device__ __forceinline__ void stage_weights(_Float16* Wl, const _Float16* Wg,
                                              int j, int tid)
{
#pragma unroll
    for (int rep = 0; rep < 8; ++rep) {
        int idx = rep * 512 + tid;      // [0, 4096) over (row n, 16B-block kb)
        int n  = idx >> 6;
        int kb = idx & 63;
        int g  = n >> 4, u = n & 15;
        const half8* src = (const half8*)(Wg + ((size_t)(g * HID_ + j * 16 + u)) * HID_ + kb * 8);
        int phys = (kb & 56) | ((kb & 7) ^ (n & 7));
        *(half8*)((char*)Wl + n * 1024 + phys * 16) = *src;
    }
}

// ---------------------------------------------------------------------------
// Persistent LSTM, fully per-WAVE self-synchronized (no block barriers after
// init). Grid = 256 x 512. ib = blockIdx & 7 (256-row batch tile, group sits
// on one XCD -- R4-R6 FETCH data confirmed), j = blockIdx >> 3 (16 hid units
// = 64 gate rows). BOTH weight matrices live in 128 KB LDS (staged once) so
// the t0->t1 restage barrier is gone; cell state in VGPRs.
//
// Per-wave protocol: wave wv consumes rows [32wv,32wv+32) of h[t-1], which
// are produced by the 8 same-wv waves of the group's 32 blocks. Producer:
// 8 agent-scope WT stores (land at the coherence point, R6-proven) ->
// s_waitcnt(0) (per-wave drain; stores acked at CP) -> lane0 relaxed CP-RMW
// add on cnt[t][ib][wv]. Consumer: lane0 relaxed CP-RMW poll (R2 lesson:
// plain loads go stale) to 32, __shfl broadcast, agent-acquire fence
// (inv; R3-R5-proven inv+load gets fresh data), then plain vector loads.
// Waves free-run and pipeline across steps; stragglers localize.
// ---------------------------------------------------------------------------
__global__ __launch_bounds__(512) void lstm_persist(
    const _Float16* __restrict__ wih16, const _Float16* __restrict__ wsum16,
    const float* __restrict__ bsum, const _Float16* __restrict__ z16,
    _Float16* __restrict__ hs, int* __restrict__ cnt)
{
    __shared__ _Float16 Wl[2][64 * 512];   // 128 KB: [0]=W_ih (t=0), [1]=W_sum

    const int tid  = threadIdx.x;
    const int ib   = blockIdx.x & 7;
    const int j    = blockIdx.x >> 3;
    const int lane = tid & 63;
    const int wv   = tid >> 6;          // wave 0..7 -> M strip of 32 rows
    const int qw   = lane >> 4;         // quad 0..3
    const int ln   = lane & 15;
    const int hid  = j * 16 + ln;

    stage_weights(Wl[0], wih16, j, tid);
    stage_weights(Wl[1], wsum16, j, tid);

    float bias[4];
#pragma unroll
    for (int g = 0; g < 4; ++g) bias[g] = bsum[g * HID_ + hid];

    float c[2][4];
#pragma unroll
    for (int mt = 0; mt < 2; ++mt)
#pragma unroll
        for (int r = 0; r < 4; ++r) c[mt][r] = 0.f;

    const int tE = (qw ^ (ln & 7)) * 16;    // swizzled byte offset, kk-even

    __syncthreads();                        // the ONLY block barrier

    for (int t = 0; t < PH_; ++t) {
        const _Float16* xx = (t == 0) ? z16 : hs + (size_t)(t - 1) * BS_ * HID_;
        const char* Bl = (const char*)Wl[t > 0 ? 1 : 0];

        if (t >= 1) {
            int v = 0;
            do {
                if (lane == 0)
                    v = __hip_atomic_fetch_add(&cnt[(t - 1) * 64 + ib * 8 + wv], 0,
                                               __ATOMIC_RELAXED,
                                               __HIP_MEMORY_SCOPE_AGENT);
                v = __shfl(v, 0);
                if (v < 32) __builtin_amdgcn_s_sleep(2);
            } while (v < 32);
            __builtin_amdgcn_fence(__ATOMIC_ACQUIRE, "agent");
        }

        floatx4 acc[2][4];                  // bias pre-folded
#pragma unroll
        for (int mt = 0; mt < 2; ++mt)
#pragma unroll
            for (int g = 0; g < 4; ++g)
                acc[mt][g] = (floatx4){bias[g], bias[g], bias[g], bias[g]};

        // A fragment: A[m = ln][k = qw*8 + jj]; depth-4 global prefetch ring
        const _Float16* A0 = xx + (size_t)(ib * 256 + wv * 32 + ln) * HID_ + qw * 8;

        half8 a0r[4], a1r[4], bA[4], bB[4];
#pragma unroll
        for (int p = 0; p < 4; ++p) {
            a0r[p] = *(const half8*)(A0 + p * 32);
            a1r[p] = *(const half8*)(A0 + 16 * HID_ + p * 32);
        }
#pragma unroll
        for (int g = 0; g < 4; ++g)
            bA[g] = *(const half8*)(Bl + (g * 16 + ln) * 1024 + tE);

#pragma unroll
        for (int kk = 0; kk < 16; ++kk) {
            half8 ca0 = a0r[kk & 3], ca1 = a1r[kk & 3];
            if (kk < 12) {
                a0r[kk & 3] = *(const half8*)(A0 + (kk + 4) * 32);
                a1r[kk & 3] = *(const half8*)(A0 + 16 * HID_ + (kk + 4) * 32);
            }
            half8* cb = (kk & 1) ? bB : bA;
            half8* nb = (kk & 1) ? bA : bB;
            if (kk < 15) {
                int k1 = kk + 1;
#pragma unroll
                for (int g = 0; g < 4; ++g) {
                    int off = (g * 16 + ln) * 1024 + (k1 >> 1) * 128 + (tE ^ ((k1 & 1) << 6));
                    nb[g] = *(const half8*)(Bl + off);
                }
            }
#pragma unroll
            for (int g = 0; g < 4; ++g) {
                acc[0][g] = __builtin_amdgcn_mfma_f32_16x16x32_f16(ca0, cb[g], acc[0][g], 0, 0, 0);
                acc[1][g] = __builtin_amdgcn_mfma_f32_16x16x32_f16(ca1, cb[g], acc[1][g], 0, 0, 0);
            }
        }

        // epilogue: C/D layout col=ln, row=qw*4+r; all 4 gates in-thread.
        // h stores agent-scope write-through (coherence point), R6-proven.
        _Float16* hb = hs + (size_t)t * BS_ * HID_
                          + (size_t)(ib * 256 + wv * 32 + qw * 4) * HID_ + hid;
#pragma unroll
        for (int mt = 0; mt < 2; ++mt) {
#pragma unroll
            for (int r = 0; r < 4; ++r) {
                float gi = acc[mt][0][r];
                float gf = acc[mt][1][r];
                float gg = acc[mt][2][r];
                float go = acc[mt][3][r];
                float cn = sigf(gf) * c[mt][r] + sigf(gi) * tanhfast(gg);
                float hn = sigf(go) * tanhfast(cn);
                c[mt][r] = cn;
                _Float16 hf = (_Float16)hn;
                short hv;
                __builtin_memcpy(&hv, &hf, 2);
                __hip_atomic_store((short*)(hb + (size_t)(mt * 16 + r) * HID_), hv,
                                   __ATOMIC_RELAXED, __HIP_MEMORY_SCOPE_AGENT);
            }
        }

        // per-wave drain: WT stores acked at the CP once vmcnt==0, then signal
        if (t < PH_ - 1) {
            __atomic_signal_fence(__ATOMIC_SEQ_CST);
            __builtin_amdgcn_s_waitcnt(0);
            __atomic_signal_fence(__ATOMIC_SEQ_CST);
            if (lane == 0)
                __hip_atomic_fetch_add(&cnt[t * 64 + ib * 8 + wv], 1,
                                       __ATOMIC_RELAXED, __HIP_MEMORY_SCOPE_AGENT);
        }
    }
}

// ---------------------------------------------------------------------------
// y[b,t,:] = hs[t][b,:] @ W_d^T + b_d. One wave per (b,t) row.
// ---------------------------------------------------------------------------
__global__ __launch_bounds__(256) void dense_kernel(
    const _Float16* __restrict__ hs, const float* __restrict__ Wd,
    const float* __restrict__ bd, float* __restrict__ y)
{
    int gw   = (blockIdx.x * 256 + threadIdx.x) >> 6;   // wave id [0, 65536)
    int lane = threadIdx.x & 63;
    int tt = gw & 31, b = gw >> 5;
    half8 h = *(const half8*)(hs + ((size_t)tt * BS_ + b) * HID_ + lane * 8);
    float s0 = 0.f, s1 = 0.f;
#pragma unroll
    for (int k = 0; k < 8; ++k) {
        float hv = (float)h[k];
        s0 += hv * Wd[lane * 8 + k];
        s1 += hv * Wd[HID_ + lane * 8 + k];
    }
#pragma unroll
    for (int m = 32; m >= 1; m >>= 1) {
        s0 += __shfl_xor(s0, m);
        s1 += __shfl_xor(s1, m);
    }
    if (lane == 0) {
        float* o = y + ((size_t)b * PH_ + tt) * 2;
        o[0] = s0 + bd[0];
        o[1] = s1 + bd[1];
    }
}

// ---------------------------------------------------------------------------
extern "C" void kernel_launch(void* const* d_in, const int* in_sizes, int n_in,
                              void* d_out, int out_size, void* d_ws, size_t ws_size,
                              hipStream_t stream)
{
    (void)in_sizes; (void)n_in; (void)out_size; (void)ws_size;
    // setup_inputs order: hist(0, unused), z(1), W_ih(2), W_hh(3), b_ih(4),
    //                     b_hh(5), W_d(6), b_d(7)
    const float* z   = (const float*)d_in[1];
    const float* Wih = (const float*)d_in[2];
    const float* Whh = (const float*)d_in[3];
    const float* bih = (const float*)d_in[4];
    const float* bhh = (const float*)d_in[5];
    const float* Wd  = (const float*)d_in[6];
    const float* bd  = (const float*)d_in[7];
    float* y = (float*)d_out;

    char* ws = (char*)d_ws;
    _Float16* hs     = (_Float16*)ws;                          // 32*2048*512*2 = 64 MB
    _Float16* z16    = (_Float16*)(ws + (size_t)67108864);     // 2 MB
    _Float16* wih16  = (_Float16*)(ws + (size_t)69206016);     // 2 MB
    _Float16* wsum16 = (_Float16*)(ws + (size_t)71303168);     // 2 MB
    float*    bsum   = (float*)   (ws + (size_t)73400320);     // 8 KB
    int*      cnt    = (int*)     (ws + (size_t)73408512);     // 2048 ints

    prep_kernel<<<4096, 256, 0, stream>>>(Wih, Whh, bih, bhh, z,
                                          wih16, wsum16, z16, bsum, cnt);

    {
        const void* k = (const void*)lstm_persist;
        void* args[] = {(void*)&wih16, (void*)&wsum16, (void*)&bsum,
                        (void*)&z16, (void*)&hs, (void*)&cnt};
        hipLaunchCooperativeKernel(k, dim3(256), dim3(512), args, 0, stream);
    }

    dense_kernel<<<16384, 256, 0, stream>>>(hs, Wd, bd, y);
}

// Round 8
// 1559.016 us; speedup vs baseline: 1.2135x; 1.2135x over previous
//
#include <hip/hip_runtime.h>
#include <hip/hip_bf16.h>

#define BS_   2048
#define HID_  512
#define PH_   32

typedef _Float16 half8 __attribute__((ext_vector_type(8)));
typedef float floatx4 __attribute__((ext_vector_type(4)));

__device__ __forceinline__ float sigf(float x) { return 1.f / (1.f + __expf(-x)); }
__device__ __forceinline__ float tanhfast(float x) {
    float e = __expf(2.f * x);          // e=inf -> 1, e->0 -> -1 : safe at extremes
    return 1.f - 2.f / (e + 1.f);
}

// ---------------------------------------------------------------------------
// Prep: fp16 weights (W_ih and W_ih+W_hh), combined bias, z16, zero the
// per-(t, ib, wv) wave counters (2048 ints).
// ---------------------------------------------------------------------------
__global__ __launch_bounds__(256) void prep_kernel(
    const float* __restrict__ Wih, const float* __restrict__ Whh,
    const float* __restrict__ bih, const float* __restrict__ bhh,
    const float* __restrict__ z,
    _Float16* __restrict__ wih16, _Float16* __restrict__ wsum16,
    _Float16* __restrict__ z16, float* __restrict__ bsum,
    int* __restrict__ cnt)
{
    int i = blockIdx.x * 256 + threadIdx.x;          // [0, 1048576)
    if (i < BS_ * HID_) z16[i] = (_Float16)z[i];
    if (i < 4 * HID_ * HID_) {
        float a = Wih[i];
        wih16[i]  = (_Float16)a;
        wsum16[i] = (_Float16)(a + Whh[i]);
    }
    if (i < 4 * HID_) bsum[i] = bih[i] + bhh[i];
    if (i < 2048) cnt[i] = 0;
}

// ---------------------------------------------------------------------------
__device__ __forceinline__ void stage_weights(_Float16* Wl, const _Float16* Wg,
                                              int j, int tid)
{
#pragma unroll
    for (int rep = 0; rep < 8; ++rep) {
        int idx = rep * 512 + tid;      // [0, 4096) over (row n, 16B-block kb)
        int n  = idx >> 6;
        int kb = idx & 63;
        int g  = n >> 4, u = n & 15;
        const half8* src = (const half8*)(Wg + ((size_t)(g * HID_ + j * 16 + u)) * HID_ + kb * 8);
        int phys = (kb & 56) | ((kb & 7) ^ (n & 7));
        *(half8*)((char*)Wl + n * 1024 + phys * 16) = *src;
    }
}

// ---------------------------------------------------------------------------
// Persistent LSTM, per-WAVE self-synchronized, FENCE-FREE steady state.
// R7's 5x regression is attributed to its per-wave agent-acquire fences
// (buffer_inv storms, ~63K TCC-serialized cache-ops/dispatch); R6's proven
// protocol has zero fences. This round: R7 structure, fences deleted.
//
// Grid = 256 x 512. ib = blockIdx & 7 (256-row batch tile), j = blockIdx >> 3
// (16 hid units = 64 gate rows). Both weight matrices in 128 KB LDS (staged
// once, no restage barrier); cell state in VGPRs; no block barriers after
// init.
//
// Per-wave protocol: wave wv consumes rows [32wv,32wv+32) of h[t-1],
// produced by the 8 same-wv waves of the group's 32 blocks. Producer:
// agent-scope WT stores (land at the coherence point, R6-proven) ->
// per-wave s_waitcnt(0) (stores acked at CP) -> lane0 relaxed CP-RMW add.
// Consumer: lane0 relaxed CP-RMW poll (plain loads go stale -- R2) to 32,
// __shfl broadcast, compiler-only signal_fence (no hoisting), then plain
// vector loads: h[t-1] lines were never cached on this XCD before every
// producer's CP ack, so the L2/L1 fills are fresh (R6-proven argument).
// ---------------------------------------------------------------------------
__global__ __launch_bounds__(512) void lstm_persist(
    const _Float16* __restrict__ wih16, const _Float16* __restrict__ wsum16,
    const float* __restrict__ bsum, const _Float16* __restrict__ z16,
    _Float16* __restrict__ hs, int* __restrict__ cnt)
{
    __shared__ _Float16 Wl[2][64 * 512];   // 128 KB: [0]=W_ih (t=0), [1]=W_sum

    const int tid  = threadIdx.x;
    const int ib   = blockIdx.x & 7;
    const int j    = blockIdx.x >> 3;
    const int lane = tid & 63;
    const int wv   = tid >> 6;          // wave 0..7 -> M strip of 32 rows
    const int qw   = lane >> 4;         // quad 0..3
    const int ln   = lane & 15;
    const int hid  = j * 16 + ln;

    stage_weights(Wl[0], wih16, j, tid);
    stage_weights(Wl[1], wsum16, j, tid);

    float bias[4];
#pragma unroll
    for (int g = 0; g < 4; ++g) bias[g] = bsum[g * HID_ + hid];

    float c[2][4];
#pragma unroll
    for (int mt = 0; mt < 2; ++mt)
#pragma unroll
        for (int r = 0; r < 4; ++r) c[mt][r] = 0.f;

    const int tE = (qw ^ (ln & 7)) * 16;    // swizzled byte offset, kk-even

    __syncthreads();                        // the ONLY block barrier

    for (int t = 0; t < PH_; ++t) {
        const _Float16* xx = (t == 0) ? z16 : hs + (size_t)(t - 1) * BS_ * HID_;
        const char* Bl = (const char*)Wl[t > 0 ? 1 : 0];

        if (t >= 1) {
            int v = 0;
            do {
                if (lane == 0)
                    v = __hip_atomic_fetch_add(&cnt[(t - 1) * 64 + ib * 8 + wv], 0,
                                               __ATOMIC_RELAXED,
                                               __HIP_MEMORY_SCOPE_AGENT);
                v = __shfl(v, 0);
                if (v < 32) __builtin_amdgcn_s_sleep(1);
            } while (v < 32);
            __atomic_signal_fence(__ATOMIC_SEQ_CST);   // compiler-only: no hoist
        }

        floatx4 acc[2][4];                  // bias pre-folded
#pragma unroll
        for (int mt = 0; mt < 2; ++mt)
#pragma unroll
            for (int g = 0; g < 4; ++g)
                acc[mt][g] = (floatx4){bias[g], bias[g], bias[g], bias[g]};

        // A fragment: A[m = ln][k = qw*8 + jj]; depth-4 global prefetch ring
        const _Float16* A0 = xx + (size_t)(ib * 256 + wv * 32 + ln) * HID_ + qw * 8;

        half8 a0r[4], a1r[4], bA[4], bB[4];
#pragma unroll
        for (int p = 0; p < 4; ++p) {
            a0r[p] = *(const half8*)(A0 + p * 32);
            a1r[p] = *(const half8*)(A0 + 16 * HID_ + p * 32);
        }
#pragma unroll
        for (int g = 0; g < 4; ++g)
            bA[g] = *(const half8*)(Bl + (g * 16 + ln) * 1024 + tE);

#pragma unroll
        for (int kk = 0; kk < 16; ++kk) {
            half8 ca0 = a0r[kk & 3], ca1 = a1r[kk & 3];
            if (kk < 12) {
                a0r[kk & 3] = *(const half8*)(A0 + (kk + 4) * 32);
                a1r[kk & 3] = *(const half8*)(A0 + 16 * HID_ + (kk + 4) * 32);
            }
            half8* cb = (kk & 1) ? bB : bA;
            half8* nb = (kk & 1) ? bA : bB;
            if (kk < 15) {
                int k1 = kk + 1;
#pragma unroll
                for (int g = 0; g < 4; ++g) {
                    int off = (g * 16 + ln) * 1024 + (k1 >> 1) * 128 + (tE ^ ((k1 & 1) << 6));
                    nb[g] = *(const half8*)(Bl + off);
                }
            }
#pragma unroll
            for (int g = 0; g < 4; ++g) {
                acc[0][g] = __builtin_amdgcn_mfma_f32_16x16x32_f16(ca0, cb[g], acc[0][g], 0, 0, 0);
                acc[1][g] = __builtin_amdgcn_mfma_f32_16x16x32_f16(ca1, cb[g], acc[1][g], 0, 0, 0);
            }
        }

        // epilogue: C/D layout col=ln, row=qw*4+r; all 4 gates in-thread.
        // h stores agent-scope write-through (coherence point), R6-proven.
        _Float16* hb = hs + (size_t)t * BS_ * HID_
                          + (size_t)(ib * 256 + wv * 32 + qw * 4) * HID_ + hid;
#pragma unroll
        for (int mt = 0; mt < 2; ++mt) {
#pragma unroll
            for (int r = 0; r < 4; ++r) {
                float gi = acc[mt][0][r];
                float gf = acc[mt][1][r];
                float gg = acc[mt][2][r];
                float go = acc[mt][3][r];
                float cn = sigf(gf) * c[mt][r] + sigf(gi) * tanhfast(gg);
                float hn = sigf(go) * tanhfast(cn);
                c[mt][r] = cn;
                _Float16 hf = (_Float16)hn;
                short hv;
                __builtin_memcpy(&hv, &hf, 2);
                __hip_atomic_store((short*)(hb + (size_t)(mt * 16 + r) * HID_), hv,
                                   __ATOMIC_RELAXED, __HIP_MEMORY_SCOPE_AGENT);
            }
        }

        // per-wave drain: WT stores acked at the CP once vmcnt==0, then signal
        if (t < PH_ - 1) {
            __atomic_signal_fence(__ATOMIC_SEQ_CST);
            __builtin_amdgcn_s_waitcnt(0);
            __atomic_signal_fence(__ATOMIC_SEQ_CST);
            if (lane == 0)
                __hip_atomic_fetch_add(&cnt[t * 64 + ib * 8 + wv], 1,
                                       __ATOMIC_RELAXED, __HIP_MEMORY_SCOPE_AGENT);
        }
    }
}

// ---------------------------------------------------------------------------
// y[b,t,:] = hs[t][b,:] @ W_d^T + b_d. One wave per (b,t) row.
// ---------------------------------------------------------------------------
__global__ __launch_bounds__(256) void dense_kernel(
    const _Float16* __restrict__ hs, const float* __restrict__ Wd,
    const float* __restrict__ bd, float* __restrict__ y)
{
    int gw   = (blockIdx.x * 256 + threadIdx.x) >> 6;   // wave id [0, 65536)
    int lane = threadIdx.x & 63;
    int tt = gw & 31, b = gw >> 5;
    half8 h = *(const half8*)(hs + ((size_t)tt * BS_ + b) * HID_ + lane * 8);
    float s0 = 0.f, s1 = 0.f;
#pragma unroll
    for (int k = 0; k < 8; ++k) {
        float hv = (float)h[k];
        s0 += hv * Wd[lane * 8 + k];
        s1 += hv * Wd[HID_ + lane * 8 + k];
    }
#pragma unroll
    for (int m = 32; m >= 1; m >>= 1) {
        s0 += __shfl_xor(s0, m);
        s1 += __shfl_xor(s1, m);
    }
    if (lane == 0) {
        float* o = y + ((size_t)b * PH_ + tt) * 2;
        o[0] = s0 + bd[0];
        o[1] = s1 + bd[1];
    }
}

// ---------------------------------------------------------------------------
extern "C" void kernel_launch(void* const* d_in, const int* in_sizes, int n_in,
                              void* d_out, int out_size, void* d_ws, size_t ws_size,
                              hipStream_t stream)
{
    (void)in_sizes; (void)n_in; (void)out_size; (void)ws_size;
    // setup_inputs order: hist(0, unused), z(1), W_ih(2), W_hh(3), b_ih(4),
    //                     b_hh(5), W_d(6), b_d(7)
    const float* z   = (const float*)d_in[1];
    const float* Wih = (const float*)d_in[2];
    const float* Whh = (const float*)d_in[3];
    const float* bih = (const float*)d_in[4];
    const float* bhh = (const float*)d_in[5];
    const float* Wd  = (const float*)d_in[6];
    const float* bd  = (const float*)d_in[7];
    float* y = (float*)d_out;

    char* ws = (char*)d_ws;
    _Float16* hs     = (_Float16*)ws;                          // 32*2048*512*2 = 64 MB
    _Float16* z16    = (_Float16*)(ws + (size_t)67108864);     // 2 MB
    _Float16* wih16  = (_Float16*)(ws + (size_t)69206016);     // 2 MB
    _Float16* wsum16 = (_Float16*)(ws + (size_t)71303168);     // 2 MB
    float*    bsum   = (float*)   (ws + (size_t)73400320);     // 8 KB
    int*      cnt    = (int*)     (ws + (size_t)73408512);     // 2048 ints

    prep_kernel<<<4096, 256, 0, stream>>>(Wih, Whh, bih, bhh, z,
                                          wih16, wsum16, z16, bsum, cnt);

    {
        const void* k = (const void*)lstm_persist;
        void* args[] = {(void*)&wih16, (void*)&wsum16, (void*)&bsum,
                        (void*)&z16, (void*)&hs, (void*)&cnt};
        hipLaunchCooperativeKernel(k, dim3(256), dim3(512), args, 0, stream);
    }

    dense_kernel<<<16384, 256, 0, stream>>>(hs, Wd, bd, y);
}

// Round 9
// 425.621 us; speedup vs baseline: 4.4450x; 3.6629x over previous
//
#include <hip/hip_runtime.h>
#include <hip/hip_bf16.h>

#define BS_   2048
#define HID_  512
#define PH_   32
#define GRP_  16        // blocks per sync group (was 32 in R6)

typedef _Float16 half8 __attribute__((ext_vector_type(8)));
typedef float floatx4 __attribute__((ext_vector_type(4)));

__device__ __forceinline__ float sigf(float x) { return 1.f / (1.f + __expf(-x)); }
__device__ __forceinline__ float tanhfast(float x) {
    float e = __expf(2.f * x);          // e=inf -> 1, e->0 -> -1 : safe at extremes
    return 1.f - 2.f / (e + 1.f);
}

// ---------------------------------------------------------------------------
// Prep: fp16 weights (W_ih, W_ih+W_hh), combined bias, z16, zero the step
// counters (16 groups x 32 steps = 512 ints; each group's 32 ints = 2 cache
// lines, no cross-group line sharing).
// ---------------------------------------------------------------------------
__global__ __launch_bounds__(256) void prep_kernel(
    const float* __restrict__ Wih, const float* __restrict__ Whh,
    const float* __restrict__ bih, const float* __restrict__ bhh,
    const float* __restrict__ z,
    _Float16* __restrict__ wih16, _Float16* __restrict__ wsum16,
    _Float16* __restrict__ z16, float* __restrict__ bsum,
    int* __restrict__ cnt)
{
    int i = blockIdx.x * 256 + threadIdx.x;          // [0, 1048576)
    if (i < BS_ * HID_) z16[i] = (_Float16)z[i];
    if (i < 4 * HID_ * HID_) {
        float a = Wih[i];
        wih16[i]  = (_Float16)a;
        wsum16[i] = (_Float16)(a + Whh[i]);
    }
    if (i < 4 * HID_) bsum[i] = bih[i] + bhh[i];
    if (i < 512) cnt[i] = 0;
}

// ---------------------------------------------------------------------------
// Stage a 32-hid weight slice: 128 gate rows x 512 K fp16 = 128 KB LDS,
// XOR-swizzled on 16B blocks (row&7 == ln&7 at read time, conflict-free).
// ---------------------------------------------------------------------------
__device__ __forceinline__ void stage_weights(_Float16* Wl, const _Float16* Wg,
                                              int j, int tid)
{
#pragma unroll
    for (int rep = 0; rep < 16; ++rep) {
        int idx = rep * 512 + tid;      // [0, 8192): row n in [0,128), kb in [0,64)
        int n  = idx >> 6;
        int kb = idx & 63;
        int g  = n >> 5, u = n & 31;    // gate, hid-within-slice
        const half8* src = (const half8*)(Wg + ((size_t)(g * HID_ + j * 32 + u)) * HID_ + kb * 8);
        int phys = (kb & 56) | ((kb & 7) ^ (n & 7));
        *(half8*)((char*)Wl + n * 1024 + phys * 16) = *src;
    }
}

// ---------------------------------------------------------------------------
// Persistent LSTM, R6-proven block-level protocol, GROUP SIZE 16.
// Grid = 256 x 512. ib = blockIdx & 15 (128-row batch tile), j = blockIdx>>4
// (32 hid units = 128 gate rows, 128 KB LDS, single weight matrix restaged
// once at the t=0 tail). Wave wv: M-strip (wv&3)*32 rows, hid-half wv>>2 —
// same 2Mx4N inner loop as R6 (0.5 B-reads/MFMA, all 4 gates in-thread).
//
// Sync (byte-identical semantics to R6, fence-free): producer h stores are
// agent-scope write-through (land at the CP); __syncthreads drains vmcnt;
// tid0 signals with a relaxed CP-RMW add. Consumer tid0 polls with relaxed
// CP-RMW (plain loads go stale -- R2) to GRP_, then __syncthreads; plain
// loads pull fresh CP data (lines never cached on this XCD this dispatch).
// Per-wave variants of this protocol regressed 4-5x (R7/R8: poll storms on
// shared counter lines) -- do not re-attempt.
// ---------------------------------------------------------------------------
__global__ __launch_bounds__(512) void lstm_persist(
    const _Float16* __restrict__ wih16, const _Float16* __restrict__ wsum16,
    const float* __restrict__ bsum, const _Float16* __restrict__ z16,
    _Float16* __restrict__ hs, int* __restrict__ cnt)
{
    __shared__ _Float16 Wl[128 * 512];   // 128 KB

    const int tid  = threadIdx.x;
    const int ib   = blockIdx.x & 15;
    const int j    = blockIdx.x >> 4;
    const int lane = tid & 63;
    const int wv   = tid >> 6;
    const int ms   = wv & 3;            // M-strip: 32 rows of the 128-row tile
    const int hh   = wv >> 2;           // hid half: 0 -> units 0..15, 1 -> 16..31
    const int qw   = lane >> 4;         // quad 0..3
    const int ln   = lane & 15;
    const int hid  = j * 32 + hh * 16 + ln;

    stage_weights(Wl, wih16, j, tid);

    float bias[4];
#pragma unroll
    for (int g = 0; g < 4; ++g) bias[g] = bsum[g * HID_ + hid];

    float c[2][4];
#pragma unroll
    for (int mt = 0; mt < 2; ++mt)
#pragma unroll
        for (int r = 0; r < 4; ++r) c[mt][r] = 0.f;

    const char* Bl = (const char*)Wl;
    const int tE = (qw ^ (ln & 7)) * 16;    // swizzled byte offset, kk-even
    const int rowB = hh * 16 + ln;          // LDS row within a gate's 32 rows

    __syncthreads();

    for (int t = 0; t < PH_; ++t) {
        const _Float16* xx = (t == 0) ? z16 : hs + (size_t)(t - 1) * BS_ * HID_;

        if (t >= 1) {
            if (tid == 0) {
                while (__hip_atomic_fetch_add(&cnt[ib * 32 + t - 1], 0,
                                              __ATOMIC_RELAXED,
                                              __HIP_MEMORY_SCOPE_AGENT) < GRP_) {
                    __builtin_amdgcn_s_sleep(1);
                }
            }
            __syncthreads();    // orders all following loads after the poll
        }

        floatx4 acc[2][4];                  // bias pre-folded
#pragma unroll
        for (int mt = 0; mt < 2; ++mt)
#pragma unroll
            for (int g = 0; g < 4; ++g)
                acc[mt][g] = (floatx4){bias[g], bias[g], bias[g], bias[g]};

        // A fragment: A[m = ln][k = qw*8 + jj]; depth-4 global prefetch ring
        const _Float16* A0 = xx + (size_t)(ib * 128 + ms * 32 + ln) * HID_ + qw * 8;

        half8 a0r[4], a1r[4], bA[4], bB[4];
#pragma unroll
        for (int p = 0; p < 4; ++p) {
            a0r[p] = *(const half8*)(A0 + p * 32);
            a1r[p] = *(const half8*)(A0 + 16 * HID_ + p * 32);
        }
#pragma unroll
        for (int g = 0; g < 4; ++g)
            bA[g] = *(const half8*)(Bl + (g * 32 + rowB) * 1024 + tE);

#pragma unroll
        for (int kk = 0; kk < 16; ++kk) {
            half8 ca0 = a0r[kk & 3], ca1 = a1r[kk & 3];
            if (kk < 12) {
                a0r[kk & 3] = *(const half8*)(A0 + (kk + 4) * 32);
                a1r[kk & 3] = *(const half8*)(A0 + 16 * HID_ + (kk + 4) * 32);
            }
            half8* cb = (kk & 1) ? bB : bA;
            half8* nb = (kk & 1) ? bA : bB;
            if (kk < 15) {
                int k1 = kk + 1;
#pragma unroll
                for (int g = 0; g < 4; ++g) {
                    int off = (g * 32 + rowB) * 1024 + (k1 >> 1) * 128 + (tE ^ ((k1 & 1) << 6));
                    nb[g] = *(const half8*)(Bl + off);
                }
            }
#pragma unroll
            for (int g = 0; g < 4; ++g) {
                acc[0][g] = __builtin_amdgcn_mfma_f32_16x16x32_f16(ca0, cb[g], acc[0][g], 0, 0, 0);
                acc[1][g] = __builtin_amdgcn_mfma_f32_16x16x32_f16(ca1, cb[g], acc[1][g], 0, 0, 0);
            }
        }

        // epilogue: C/D layout col=ln, row=qw*4+r; all 4 gates in-thread.
        // h stores agent-scope write-through (coherence point), R6-proven.
        _Float16* hb = hs + (size_t)t * BS_ * HID_
                          + (size_t)(ib * 128 + ms * 32 + qw * 4) * HID_ + hid;
#pragma unroll
        for (int mt = 0; mt < 2; ++mt) {
#pragma unroll
            for (int r = 0; r < 4; ++r) {
                float gi = acc[mt][0][r];
                float gf = acc[mt][1][r];
                float gg = acc[mt][2][r];
                float go = acc[mt][3][r];
                float cn = sigf(gf) * c[mt][r] + sigf(gi) * tanhfast(gg);
                float hn = sigf(go) * tanhfast(cn);
                c[mt][r] = cn;
                _Float16 hf = (_Float16)hn;
                short hv;
                __builtin_memcpy(&hv, &hf, 2);
                __hip_atomic_store((short*)(hb + (size_t)(mt * 16 + r) * HID_), hv,
                                   __ATOMIC_RELAXED, __HIP_MEMORY_SCOPE_AGENT);
            }
        }

        // Barrier drains every wave's stores (vmcnt(0) -> acked at CP for WT
        // stores), then ONE relaxed CP-RMW signals the group.
        __syncthreads();
        if (t == 0) {
            if (tid == 0)
                __hip_atomic_fetch_add(&cnt[ib * 32], 1,
                                       __ATOMIC_RELAXED, __HIP_MEMORY_SCOPE_AGENT);
            stage_weights(Wl, wsum16, j, tid);   // switch to W_ih+W_hh (once)
            __syncthreads();
        } else if (t < PH_ - 1) {
            if (tid == 0)
                __hip_atomic_fetch_add(&cnt[ib * 32 + t], 1,
                                       __ATOMIC_RELAXED, __HIP_MEMORY_SCOPE_AGENT);
        }
    }
}

// ---------------------------------------------------------------------------
// y[b,t,:] = hs[t][b,:] @ W_d^T + b_d. One wave per (b,t) row.
// ---------------------------------------------------------------------------
__global__ __launch_bounds__(256) void dense_kernel(
    const _Float16* __restrict__ hs, const float* __restrict__ Wd,
    const float* __restrict__ bd, float* __restrict__ y)
{
    int gw   = (blockIdx.x * 256 + threadIdx.x) >> 6;   // wave id [0, 65536)
    int lane = threadIdx.x & 63;
    int tt = gw & 31, b = gw >> 5;
    half8 h = *(const half8*)(hs + ((size_t)tt * BS_ + b) * HID_ + lane * 8);
    float s0 = 0.f, s1 = 0.f;
#pragma unroll
    for (int k = 0; k < 8; ++k) {
        float hv = (float)h[k];
        s0 += hv * Wd[lane * 8 + k];
        s1 += hv * Wd[HID_ + lane * 8 + k];
    }
#pragma unroll
    for (int m = 32; m >= 1; m >>= 1) {
        s0 += __shfl_xor(s0, m);
        s1 += __shfl_xor(s1, m);
    }
    if (lane == 0) {
        float* o = y + ((size_t)b * PH_ + tt) * 2;
        o[0] = s0 + bd[0];
        o[1] = s1 + bd[1];
    }
}

// ---------------------------------------------------------------------------
extern "C" void kernel_launch(void* const* d_in, const int* in_sizes, int n_in,
                              void* d_out, int out_size, void* d_ws, size_t ws_size,
                              hipStream_t stream)
{
    (void)in_sizes; (void)n_in; (void)out_size; (void)ws_size;
    // setup_inputs order: hist(0, unused), z(1), W_ih(2), W_hh(3), b_ih(4),
    //                     b_hh(5), W_d(6), b_d(7)
    const float* z   = (const float*)d_in[1];
    const float* Wih = (const float*)d_in[2];
    const float* Whh = (const float*)d_in[3];
    const float* bih = (const float*)d_in[4];
    const float* bhh = (const float*)d_in[5];
    const float* Wd  = (const float*)d_in[6];
    const float* bd  = (const float*)d_in[7];
    float* y = (float*)d_out;

    char* ws = (char*)d_ws;
    _Float16* hs     = (_Float16*)ws;                          // 32*2048*512*2 = 64 MB
    _Float16* z16    = (_Float16*)(ws + (size_t)67108864);     // 2 MB
    _Float16* wih16  = (_Float16*)(ws + (size_t)69206016);     // 2 MB
    _Float16* wsum16 = (_Float16*)(ws + (size_t)71303168);     // 2 MB
    float*    bsum   = (float*)   (ws + (size_t)73400320);     // 8 KB
    int*      cnt    = (int*)     (ws + (size_t)73408512);     // 512 ints

    prep_kernel<<<4096, 256, 0, stream>>>(Wih, Whh, bih, bhh, z,
                                          wih16, wsum16, z16, bsum, cnt);

    {
        const void* k = (const void*)lstm_persist;
        void* args[] = {(void*)&wih16, (void*)&wsum16, (void*)&bsum,
                        (void*)&z16, (void*)&hs, (void*)&cnt};
        hipLaunchCooperativeKernel(k, dim3(256), dim3(512), args, 0, stream);
    }

    dense_kernel<<<16384, 256, 0, stream>>>(hs, Wd, bd, y);
}